// Round 6
// baseline (125.947 us; speedup 1.0000x reference)
//
#include <hip/hip_runtime.h>

#define NB    256   // neighbors
#define DIN   64
#define LATD  128
#define ECD   32

typedef __attribute__((ext_vector_type(8))) __bf16 bf16x8;
typedef __attribute__((ext_vector_type(4))) float f32x4;

#define XS_STRIDE 72   // ws row stride for WcT/WfT (bf16 elems)
#define EC_STRIDE 40   // 32 data + 8 pad (LDS bank spread)
#define WA_STRIDE 40

// d_ws layout (unsigned short elements)
#define WS_WC 0                     // WcT  [32][72]
#define WS_WF (32 * 72)             // WfT  [128][72]
#define WS_WA (32 * 72 + 128 * 72)  // WaTm [128][40]  (Wa rows 32..63, transposed, *log2e)

#define MFMA(a, b, c) __builtin_amdgcn_mfma_f32_16x16x32_bf16((a), (b), (c), 0, 0, 0)

__device__ __forceinline__ unsigned short f2bf(float f) {
    unsigned u = __builtin_bit_cast(unsigned, f);
    u += 0x7fffu + ((u >> 16) & 1u);   // round-to-nearest-even
    return (unsigned short)(u >> 16);
}

// Packed f32->bf16 RNE: 1 instruction per 2 elements (gfx950; no builtin).
// Plain VALU op -> no TRANS hazard, safe as opaque asm (verified r2/r3/r5).
__device__ __forceinline__ unsigned cvt2(float lo, float hi) {
    unsigned r;
    asm("v_cvt_pk_bf16_f32 %0, %1, %2" : "=v"(r) : "v"(lo), "v"(hi));
    return r;
}

// Single-instruction exp2. r4 LESSON: raw `asm("v_exp_f32")` FAILS —
// TRANS-op results need a wait state before a dependent VALU read, and the
// compiler's hazard recognizer can't see through opaque asm (absmax 1.5).
// The builtin emits the same v_exp_f32 with compiler-managed hazards (r5:
// verified correct, part of the 128.0 -> 125.5 gain).
#if __has_builtin(__builtin_amdgcn_exp2f)
__device__ __forceinline__ float fexp2(float x) {
    return __builtin_amdgcn_exp2f(x);
}
#else
__device__ __forceinline__ float fexp2(float x) {
    float r;
    asm("v_exp_f32 %0, %1\n\ts_nop 1" : "=v"(r) : "v"(x));
    return r;
}
#endif

__device__ __forceinline__ bf16x8 pack8(float4 a, float4 b) {
    union { unsigned u[4]; bf16x8 v; } r;
    r.u[0] = cvt2(a.x, a.y);
    r.u[1] = cvt2(a.z, a.w);
    r.u[2] = cvt2(b.x, b.y);
    r.u[3] = cvt2(b.z, b.w);
    return r.v;
}

// Pre-transpose weights into bf16 B-fragment-friendly [n][k] layouts in d_ws.
// Wa rows 32..63 are pre-scaled by log2e so the kernel can use exp2 directly.
__global__ __launch_bounds__(256) void prep_kernel(
    const float* __restrict__ Wc, const float* __restrict__ Wf,
    const float* __restrict__ Wa, unsigned short* __restrict__ ws)
{
    int t = blockIdx.x * blockDim.x + threadIdx.x;
    int stride = gridDim.x * blockDim.x;
    for (int i = t; i < 32 * 64; i += stride) {
        int n = i >> 6, k = i & 63;
        ws[WS_WC + n * XS_STRIDE + k] = f2bf(Wc[k * ECD + n]);
    }
    for (int i = t; i < 128 * 64; i += stride) {
        int n = i >> 6, k = i & 63;
        ws[WS_WF + n * XS_STRIDE + k] = f2bf(Wf[k * LATD + n]);
    }
    for (int i = t; i < 128 * 32; i += stride) {
        int n = i >> 5, k = i & 31;
        ws[WS_WA + n * WA_STRIDE + k] = f2bf(Wa[(ECD + k) * LATD + n] * 1.44269504f);
    }
}

// TWO batch elements per block (b, b+512), software-pipelined: X[b1]'s
// HBM loads are issued right after X[b0] is packed, so b1's full memory
// latency hides under b0's g-loop + epilogue. r5 diagnosis: with 1024
// blocks (= exactly resident), the X-load phase had nothing to overlap
// with (HBM 16% peak, VALUBusy 30%, MfmaUtil 6% — pure latency exposure).
// At 512 blocks occupancy is grid-limited (2 blocks/CU, 2 waves/SIMD), so
// the 64 VGPRs of in-flight prefetch are free (__launch_bounds__(256,2)
// -> 256-VGPR budget).
// Shared reuse across elements is race-free: ecs rows are wave-private;
// aggnum/wlpart reuse is ordered by the existing barriers (any e=1 write
// transitively follows a barrier after all e=0 reads).
// Key algebra (verified): self_rep/mean_rep/ba constant along n -> cancel
// in softmax(axis=n); att = softmax_n(enc_comm @ Wa[32:64]); local_data /
// Wa[0:32] / Wa[64:96] / ba never touch the output.
__global__ __launch_bounds__(256, 2) void arm_main(
    const float* __restrict__ xg,   // neighbor [B][256][64]
    const float* __restrict__ bcv,  // bc [32]
    const float* __restrict__ bfv,  // bf [128]
    const float* __restrict__ wl,   // Wl [128][128]
    const float* __restrict__ blv,  // bl [128]
    const unsigned short* __restrict__ ws,
    float* __restrict__ out)        // [B][128]
{
    __shared__ unsigned short ecs[NB * EC_STRIDE];  // 20480 B, bf16 enc_comm
    __shared__ float aggnum[4][LATD];
    __shared__ float aggden[4][LATD];
    __shared__ float aggfull[LATD];
    __shared__ float wlpart[2][LATD];

    const int b0   = blockIdx.x;          // gridDim.x == 512
    const int b1   = blockIdx.x + 512;
    const int tid  = threadIdx.x;
    const int lane = tid & 63;
    const int w    = tid >> 6;   // wave id, owns rows 64w..64w+63 (4 m-tiles)
    const int l15  = lane & 15;
    const int q    = lane >> 4;

    const unsigned short* wfb = ws + WS_WF;
    const unsigned short* wab = ws + WS_WA;

    // ---- element-invariant front-loads: Wc frags + bc (L2) ----
    bf16x8 wfrag[2][2];   // [khalf][colblock]
    #pragma unroll
    for (int ks = 0; ks < 2; ++ks)
        #pragma unroll
        for (int nb = 0; nb < 2; ++nb)
            wfrag[ks][nb] = *reinterpret_cast<const bf16x8*>(
                &ws[WS_WC + (nb * 16 + l15) * XS_STRIDE + ks * 32 + q * 8]);
    float bc0 = bcv[l15], bc1 = bcv[16 + l15];

    // ---- issue X[b0] loads (HBM) ----
    // A-frag: row = lane&15 (within tile), k = quad*8 + j -> 8 contiguous floats.
    float4 st[4][4];
    {
        const float* xb = xg + (size_t)b0 * NB * DIN;
        #pragma unroll
        for (int t = 0; t < 4; ++t) {
            const float* p = xb + (w * 64 + t * 16 + l15) * DIN + q * 8;
            st[t][0] = *reinterpret_cast<const float4*>(p);
            st[t][1] = *reinterpret_cast<const float4*>(p + 4);
            st[t][2] = *reinterpret_cast<const float4*>(p + 32);
            st[t][3] = *reinterpret_cast<const float4*>(p + 36);
        }
    }

    #pragma unroll
    for (int e = 0; e < 2; ++e) {
        const int b = e ? b1 : b0;

        // g0 weights + bf bias (L2; issued before the pack's vmcnt wait)
        bf16x8 wf0 = *reinterpret_cast<const bf16x8*>(&wfb[l15 * XS_STRIDE + q * 8]);
        bf16x8 wf1 = *reinterpret_cast<const bf16x8*>(&wfb[l15 * XS_STRIDE + 32 + q * 8]);
        bf16x8 wag = *reinterpret_cast<const bf16x8*>(&wab[l15 * WA_STRIDE + q * 8]);
        float  bfl = bfv[l15];

        // ---- pack current element's X into A-fragments (waits on st) ----
        bf16x8 xfrag[4][2];
        #pragma unroll
        for (int t = 0; t < 4; ++t) {
            xfrag[t][0] = pack8(st[t][0], st[t][1]);
            xfrag[t][1] = pack8(st[t][2], st[t][3]);
        }

        // ---- enc_comm = relu(X*Wc + bc) -> ecs bf16 (same-wave rows only) ----
        #pragma unroll
        for (int t = 0; t < 4; ++t) {
            int rowA = w * 64 + t * 16;
            // bias folded into accumulator init (C/D col = lane&15 -> bias
            // uniform across the 4 result regs).
            f32x4 a0 = {bc0, bc0, bc0, bc0};
            f32x4 a1 = {bc1, bc1, bc1, bc1};
            #pragma unroll
            for (int ks = 0; ks < 2; ++ks) {
                a0 = MFMA(xfrag[t][ks], wfrag[ks][0], a0);
                a1 = MFMA(xfrag[t][ks], wfrag[ks][1], a1);
            }
            #pragma unroll
            for (int r = 0; r < 4; ++r) {
                int row = rowA + q * 4 + r;   // C/D: row = quad*4 + reg
                unsigned pk = cvt2(fmaxf(a0[r], 0.f), fmaxf(a1[r], 0.f));
                ecs[row * EC_STRIDE + l15]      = (unsigned short)pk;
                ecs[row * EC_STRIDE + 16 + l15] = (unsigned short)(pk >> 16);
            }
        }

        // ---- ec A-fragments held in registers across the whole g-loop ----
        bf16x8 ecfrag[4];
        #pragma unroll
        for (int t = 0; t < 4; ++t)
            ecfrag[t] = *reinterpret_cast<const bf16x8*>(
                &ecs[(w * 64 + t * 16 + l15) * EC_STRIDE + q * 8]);

        // ---- PREFETCH: issue X[b1] loads now (st regs just freed by pack).
        // Their ~900cy HBM latency hides under this element's g-loop+epilogue.
        if (e == 0) {
            const float* xb = xg + (size_t)b1 * NB * DIN;
            #pragma unroll
            for (int t = 0; t < 4; ++t) {
                const float* p = xb + (w * 64 + t * 16 + l15) * DIN + q * 8;
                st[t][0] = *reinterpret_cast<const float4*>(p);
                st[t][1] = *reinterpret_cast<const float4*>(p + 4);
                st[t][2] = *reinterpret_cast<const float4*>(p + 32);
                st[t][3] = *reinterpret_cast<const float4*>(p + 36);
            }
        }

        // ---- fused g-loop: enc_feature + logits + unnormalized softmax agg ----
        // No max-subtraction (logits O(+-3); exp2 safe), no barriers; each
        // wave emits num/den partials over its 64 n-rows. g+1 weights
        // software-prefetched.
        for (int g = 0; g < 8; ++g) {
            bf16x8 nwf0, nwf1, nwag;
            float  nbfl = 0.f;
            if (g < 7) {
                int r0 = (g + 1) * 16 + l15;
                nwf0 = *reinterpret_cast<const bf16x8*>(&wfb[r0 * XS_STRIDE + q * 8]);
                nwf1 = *reinterpret_cast<const bf16x8*>(&wfb[r0 * XS_STRIDE + 32 + q * 8]);
                nwag = *reinterpret_cast<const bf16x8*>(&wab[r0 * WA_STRIDE + q * 8]);
                nbfl = bfv[r0];
            }

            float num = 0.f, den = 0.f;
            #pragma unroll
            for (int t = 0; t < 4; ++t) {
                // bf bias folded into accumulator init; logits keep C=0 (ba cancels).
                f32x4 z = {bfl, bfl, bfl, bfl};
                z = MFMA(xfrag[t][0], wf0, z);
                f32x4 ef = MFMA(xfrag[t][1], wf1, z);
                f32x4 z2 = {0.f, 0.f, 0.f, 0.f};
                f32x4 lg = MFMA(ecfrag[t], wag, z2);
                #pragma unroll
                for (int r = 0; r < 4; ++r) {
                    float e2 = fmaxf(ef[r], 0.f);
                    float p  = fexp2(lg[r]);   // Wa pre-scaled by log2e in prep
                    num = fmaf(p, e2, num);
                    den += p;
                }
            }
            num += __shfl_xor(num, 16, 64); num += __shfl_xor(num, 32, 64);
            den += __shfl_xor(den, 16, 64); den += __shfl_xor(den, 32, 64);
            if (lane < 16) {
                aggnum[w][g * 16 + lane] = num;
                aggden[w][g * 16 + lane] = den;
            }

            if (g < 7) { wf0 = nwf0; wf1 = nwf1; wag = nwag; bfl = nbfl; }
        }
        __syncthreads();

        // ---- combine wave partials: aggregated[k] = sum(num)/sum(den) ----
        if (tid < 128) {
            float num = aggnum[0][tid] + aggnum[1][tid] + aggnum[2][tid] + aggnum[3][tid];
            float den = aggden[0][tid] + aggden[1][tid] + aggden[2][tid] + aggden[3][tid];
            aggfull[tid] = num / den;
        }
        __syncthreads();

        // ---- out = relu(agg @ Wl + bl), k-range split over thread halves ----
        {
            int c = tid & 127, h = tid >> 7;
            float acc = 0.f;
            #pragma unroll 16
            for (int k = h * 64; k < h * 64 + 64; ++k)
                acc += aggfull[k] * wl[k * LATD + c];
            wlpart[h][c] = acc;
        }
        __syncthreads();
        if (tid < 128)
            out[(size_t)b * LATD + tid] =
                fmaxf(wlpart[0][tid] + wlpart[1][tid] + blv[tid], 0.f);
    }
}

extern "C" void kernel_launch(void* const* d_in, const int* in_sizes, int n_in,
                              void* d_out, int out_size, void* d_ws, size_t ws_size,
                              hipStream_t stream)
{
    const float* xg  = (const float*)d_in[1];
    const float* wc  = (const float*)d_in[2];
    const float* bc_ = (const float*)d_in[3];
    const float* wf  = (const float*)d_in[4];
    const float* bf_ = (const float*)d_in[5];
    const float* wa  = (const float*)d_in[6];
    const float* wl  = (const float*)d_in[8];
    const float* bl_ = (const float*)d_in[9];
    unsigned short* wsp = (unsigned short*)d_ws;   // needs 33,280 B of ws
    float* out = (float*)d_out;

    prep_kernel<<<8, 256, 0, stream>>>(wc, wf, wa, wsp);
    arm_main<<<512, 256, 0, stream>>>(xg, bc_, bf_, wl, bl_, wsp, out);
}

// Round 7
// 124.671 us; speedup vs baseline: 1.0102x; 1.0102x over previous
//
#include <hip/hip_runtime.h>

#define NB    256   // neighbors
#define DIN   64
#define LATD  128
#define ECD   32

typedef __attribute__((ext_vector_type(8))) __bf16 bf16x8;
typedef __attribute__((ext_vector_type(4))) float f32x4;

#define XS_STRIDE 72   // ws row stride for WcT/WfT (bf16 elems)
#define EC_STRIDE 40   // 32 data + 8 pad (LDS bank spread)
#define WA_STRIDE 40

// d_ws layout (unsigned short elements)
#define WS_WC 0                     // WcT  [32][72]
#define WS_WF (32 * 72)             // WfT  [128][72]
#define WS_WA (32 * 72 + 128 * 72)  // WaTm [128][40]  (Wa rows 32..63, transposed, *log2e)

#define MFMA(a, b, c) __builtin_amdgcn_mfma_f32_16x16x32_bf16((a), (b), (c), 0, 0, 0)

__device__ __forceinline__ unsigned short f2bf(float f) {
    unsigned u = __builtin_bit_cast(unsigned, f);
    u += 0x7fffu + ((u >> 16) & 1u);   // round-to-nearest-even
    return (unsigned short)(u >> 16);
}

// Packed f32->bf16 RNE: 1 instruction per 2 elements (gfx950; no builtin).
// Plain VALU op -> no TRANS hazard, safe as opaque asm (verified r2..r6).
__device__ __forceinline__ unsigned cvt2(float lo, float hi) {
    unsigned r;
    asm("v_cvt_pk_bf16_f32 %0, %1, %2" : "=v"(r) : "v"(lo), "v"(hi));
    return r;
}

// Single-instruction exp2. r4 LESSON: raw `asm("v_exp_f32")` FAILS —
// TRANS-op results need a wait state before a dependent VALU read and the
// compiler's hazard recognizer can't see through opaque asm (absmax 1.5).
// The builtin emits v_exp_f32 with compiler-managed hazards (r5 verified).
#if __has_builtin(__builtin_amdgcn_exp2f)
__device__ __forceinline__ float fexp2(float x) {
    return __builtin_amdgcn_exp2f(x);
}
#else
__device__ __forceinline__ float fexp2(float x) {
    float r;
    asm("v_exp_f32 %0, %1\n\ts_nop 1" : "=v"(r) : "v"(x));
    return r;
}
#endif

__device__ __forceinline__ bf16x8 pack8(float4 a, float4 b) {
    union { unsigned u[4]; bf16x8 v; } r;
    r.u[0] = cvt2(a.x, a.y);
    r.u[1] = cvt2(a.z, a.w);
    r.u[2] = cvt2(b.x, b.y);
    r.u[3] = cvt2(b.z, b.w);
    return r.v;
}

// Pre-transpose weights into bf16 B-fragment-friendly [n][k] layouts in d_ws.
// Wa rows 32..63 are pre-scaled by log2e so the kernel can use exp2 directly.
__global__ __launch_bounds__(256) void prep_kernel(
    const float* __restrict__ Wc, const float* __restrict__ Wf,
    const float* __restrict__ Wa, unsigned short* __restrict__ ws)
{
    int t = blockIdx.x * blockDim.x + threadIdx.x;
    int stride = gridDim.x * blockDim.x;
    for (int i = t; i < 32 * 64; i += stride) {
        int n = i >> 6, k = i & 63;
        ws[WS_WC + n * XS_STRIDE + k] = f2bf(Wc[k * ECD + n]);
    }
    for (int i = t; i < 128 * 64; i += stride) {
        int n = i >> 6, k = i & 63;
        ws[WS_WF + n * XS_STRIDE + k] = f2bf(Wf[k * LATD + n]);
    }
    for (int i = t; i < 128 * 32; i += stride) {
        int n = i >> 5, k = i & 31;
        ws[WS_WA + n * WA_STRIDE + k] = f2bf(Wa[(ECD + k) * LATD + n] * 1.44269504f);
    }
}

// TWO batch elements per block, INTERLEAVED in the same g-loop (r6's
// sequential version was neutral: X latency wasn't the bottleneck; chain
// stalls are). Interleaving doubles every independent dependency chain
// (MFMA / exp / FMA-accum) per wave AND halves per-element weight + Wl
// traffic (wf0/wf1/wag/bfl and wl[] loaded once, used by both elements).
// 4-tile waves retained (r1/r3: tile-ILP beats wave count). 2 blocks/CU
// (r6: neutral vs 4). __launch_bounds__(256,2) -> 256-VGPR budget;
// estimated peak ~200.
// Key algebra (verified): self_rep/mean_rep/ba constant along n -> cancel
// in softmax(axis=n); att = softmax_n(enc_comm @ Wa[32:64]); local_data /
// Wa[0:32] / Wa[64:96] / ba never touch the output.
__global__ __launch_bounds__(256, 2) void arm_main(
    const float* __restrict__ xg,   // neighbor [B][256][64]
    const float* __restrict__ bcv,  // bc [32]
    const float* __restrict__ bfv,  // bf [128]
    const float* __restrict__ wl,   // Wl [128][128]
    const float* __restrict__ blv,  // bl [128]
    const unsigned short* __restrict__ ws,
    float* __restrict__ out)        // [B][128]
{
    __shared__ unsigned short ecs[NB * EC_STRIDE];  // 20480 B, bf16 enc_comm
    __shared__ float aggnum[2][4][LATD];            // [elem][wave][col]
    __shared__ float aggden[2][4][LATD];
    __shared__ float aggfull[2][LATD];
    __shared__ float wlpart[2][2][LATD];            // [khalf][elem][col]

    const int b0   = blockIdx.x;          // gridDim.x == 512
    const int b1   = blockIdx.x + 512;
    const int tid  = threadIdx.x;
    const int lane = tid & 63;
    const int w    = tid >> 6;   // wave id, owns rows 64w..64w+63 (4 m-tiles)
    const int l15  = lane & 15;
    const int q    = lane >> 4;

    const unsigned short* wfb = ws + WS_WF;
    const unsigned short* wab = ws + WS_WA;

    // ---- element-invariant front-loads: Wc frags + bc (L2) ----
    bf16x8 wfrag[2][2];   // [khalf][colblock]
    #pragma unroll
    for (int ks = 0; ks < 2; ++ks)
        #pragma unroll
        for (int nb = 0; nb < 2; ++nb)
            wfrag[ks][nb] = *reinterpret_cast<const bf16x8*>(
                &ws[WS_WC + (nb * 16 + l15) * XS_STRIDE + ks * 32 + q * 8]);
    float bc0 = bcv[l15], bc1 = bcv[16 + l15];

    // ---- issue X loads for BOTH elements (32 dwordx4 in flight) ----
    // A-frag: row = lane&15 (within tile), k = quad*8 + j -> 8 contiguous floats.
    float4 st0[4][4], st1[4][4];
    {
        const float* xa = xg + (size_t)b0 * NB * DIN;
        const float* xc = xg + (size_t)b1 * NB * DIN;
        #pragma unroll
        for (int t = 0; t < 4; ++t) {
            const float* p = xa + (w * 64 + t * 16 + l15) * DIN + q * 8;
            st0[t][0] = *reinterpret_cast<const float4*>(p);
            st0[t][1] = *reinterpret_cast<const float4*>(p + 4);
            st0[t][2] = *reinterpret_cast<const float4*>(p + 32);
            st0[t][3] = *reinterpret_cast<const float4*>(p + 36);
        }
        #pragma unroll
        for (int t = 0; t < 4; ++t) {
            const float* p = xc + (w * 64 + t * 16 + l15) * DIN + q * 8;
            st1[t][0] = *reinterpret_cast<const float4*>(p);
            st1[t][1] = *reinterpret_cast<const float4*>(p + 4);
            st1[t][2] = *reinterpret_cast<const float4*>(p + 32);
            st1[t][3] = *reinterpret_cast<const float4*>(p + 36);
        }
    }

    // ---- pack both elements into A-fragments (st regs die here) ----
    bf16x8 xfrag[2][4][2];
    #pragma unroll
    for (int t = 0; t < 4; ++t) {
        xfrag[0][t][0] = pack8(st0[t][0], st0[t][1]);
        xfrag[0][t][1] = pack8(st0[t][2], st0[t][3]);
    }
    #pragma unroll
    for (int t = 0; t < 4; ++t) {
        xfrag[1][t][0] = pack8(st1[t][0], st1[t][1]);
        xfrag[1][t][1] = pack8(st1[t][2], st1[t][3]);
    }

    // ---- enc_comm per element -> ecs -> ecfrag (same-wave rows; the e1
    // writes to the same ecs rows happen after e0's reads — same-wave DS
    // ops execute in order, so no barrier needed) ----
    bf16x8 ecfrag[2][4];
    #pragma unroll
    for (int e = 0; e < 2; ++e) {
        #pragma unroll
        for (int t = 0; t < 4; ++t) {
            int rowA = w * 64 + t * 16;
            // bias folded into accumulator init (C/D col = lane&15 -> bias
            // uniform across the 4 result regs).
            f32x4 a0 = {bc0, bc0, bc0, bc0};
            f32x4 a1 = {bc1, bc1, bc1, bc1};
            #pragma unroll
            for (int ks = 0; ks < 2; ++ks) {
                a0 = MFMA(xfrag[e][t][ks], wfrag[ks][0], a0);
                a1 = MFMA(xfrag[e][t][ks], wfrag[ks][1], a1);
            }
            #pragma unroll
            for (int r = 0; r < 4; ++r) {
                int row = rowA + q * 4 + r;   // C/D: row = quad*4 + reg
                unsigned pk = cvt2(fmaxf(a0[r], 0.f), fmaxf(a1[r], 0.f));
                ecs[row * EC_STRIDE + l15]      = (unsigned short)pk;
                ecs[row * EC_STRIDE + 16 + l15] = (unsigned short)(pk >> 16);
            }
        }
        #pragma unroll
        for (int t = 0; t < 4; ++t)
            ecfrag[e][t] = *reinterpret_cast<const bf16x8*>(
                &ecs[(w * 64 + t * 16 + l15) * EC_STRIDE + q * 8]);
    }

    // ---- fused g-loop, both elements interleaved: enc_feature + logits +
    // unnormalized softmax agg. Weights loaded ONCE per g for both elements;
    // g+1 weights software-prefetched. No max-subtraction (logits O(+-3)).
    bf16x8 wf0 = *reinterpret_cast<const bf16x8*>(&wfb[l15 * XS_STRIDE + q * 8]);
    bf16x8 wf1 = *reinterpret_cast<const bf16x8*>(&wfb[l15 * XS_STRIDE + 32 + q * 8]);
    bf16x8 wag = *reinterpret_cast<const bf16x8*>(&wab[l15 * WA_STRIDE + q * 8]);
    float  bfl = bfv[l15];

    for (int g = 0; g < 8; ++g) {
        bf16x8 nwf0, nwf1, nwag;
        float  nbfl = 0.f;
        if (g < 7) {
            int r0 = (g + 1) * 16 + l15;
            nwf0 = *reinterpret_cast<const bf16x8*>(&wfb[r0 * XS_STRIDE + q * 8]);
            nwf1 = *reinterpret_cast<const bf16x8*>(&wfb[r0 * XS_STRIDE + 32 + q * 8]);
            nwag = *reinterpret_cast<const bf16x8*>(&wab[r0 * WA_STRIDE + q * 8]);
            nbfl = bfv[r0];
        }

        float num0 = 0.f, den0 = 0.f, num1 = 0.f, den1 = 0.f;
        #pragma unroll
        for (int t = 0; t < 4; ++t) {
            // element 0
            f32x4 za = {bfl, bfl, bfl, bfl};
            za = MFMA(xfrag[0][t][0], wf0, za);
            f32x4 efa = MFMA(xfrag[0][t][1], wf1, za);
            f32x4 zz0 = {0.f, 0.f, 0.f, 0.f};
            f32x4 lga = MFMA(ecfrag[0][t], wag, zz0);
            // element 1 (independent chain)
            f32x4 zb = {bfl, bfl, bfl, bfl};
            zb = MFMA(xfrag[1][t][0], wf0, zb);
            f32x4 efb = MFMA(xfrag[1][t][1], wf1, zb);
            f32x4 zz1 = {0.f, 0.f, 0.f, 0.f};
            f32x4 lgb = MFMA(ecfrag[1][t], wag, zz1);
            #pragma unroll
            for (int r = 0; r < 4; ++r) {
                float ea = fmaxf(efa[r], 0.f);
                float pa = fexp2(lga[r]);   // Wa pre-scaled by log2e in prep
                num0 = fmaf(pa, ea, num0);
                den0 += pa;
                float eb = fmaxf(efb[r], 0.f);
                float pb = fexp2(lgb[r]);
                num1 = fmaf(pb, eb, num1);
                den1 += pb;
            }
        }
        num0 += __shfl_xor(num0, 16, 64); num0 += __shfl_xor(num0, 32, 64);
        den0 += __shfl_xor(den0, 16, 64); den0 += __shfl_xor(den0, 32, 64);
        num1 += __shfl_xor(num1, 16, 64); num1 += __shfl_xor(num1, 32, 64);
        den1 += __shfl_xor(den1, 16, 64); den1 += __shfl_xor(den1, 32, 64);
        if (lane < 16) {
            aggnum[0][w][g * 16 + lane] = num0;
            aggden[0][w][g * 16 + lane] = den0;
            aggnum[1][w][g * 16 + lane] = num1;
            aggden[1][w][g * 16 + lane] = den1;
        }

        if (g < 7) { wf0 = nwf0; wf1 = nwf1; wag = nwag; bfl = nbfl; }
    }
    __syncthreads();

    // ---- combine wave partials (both halves of the block active) ----
    {
        int e = tid >> 7, c = tid & 127;
        float num = aggnum[e][0][c] + aggnum[e][1][c] + aggnum[e][2][c] + aggnum[e][3][c];
        float den = aggden[e][0][c] + aggden[e][1][c] + aggden[e][2][c] + aggden[e][3][c];
        aggfull[e][c] = num / den;
    }
    __syncthreads();

    // ---- out = relu(agg @ Wl + bl): wl loaded ONCE, used for both elems ----
    {
        int c = tid & 127, h = tid >> 7;
        float acc0 = 0.f, acc1 = 0.f;
        #pragma unroll 16
        for (int k = h * 64; k < h * 64 + 64; ++k) {
            float wv = wl[k * LATD + c];
            acc0 = fmaf(aggfull[0][k], wv, acc0);
            acc1 = fmaf(aggfull[1][k], wv, acc1);
        }
        wlpart[h][0][c] = acc0;
        wlpart[h][1][c] = acc1;
    }
    __syncthreads();
    {
        int e = tid >> 7, c = tid & 127;
        out[(size_t)(e ? b1 : b0) * LATD + c] =
            fmaxf(wlpart[0][e][c] + wlpart[1][e][c] + blv[c], 0.f);
    }
}

extern "C" void kernel_launch(void* const* d_in, const int* in_sizes, int n_in,
                              void* d_out, int out_size, void* d_ws, size_t ws_size,
                              hipStream_t stream)
{
    const float* xg  = (const float*)d_in[1];
    const float* wc  = (const float*)d_in[2];
    const float* bc_ = (const float*)d_in[3];
    const float* wf  = (const float*)d_in[4];
    const float* bf_ = (const float*)d_in[5];
    const float* wa  = (const float*)d_in[6];
    const float* wl  = (const float*)d_in[8];
    const float* bl_ = (const float*)d_in[9];
    unsigned short* wsp = (unsigned short*)d_ws;   // needs 33,280 B of ws
    float* out = (float*)d_out;

    prep_kernel<<<8, 256, 0, stream>>>(wc, wf, wa, wsp);
    arm_main<<<512, 256, 0, stream>>>(xg, bc_, bf_, wl, bl_, wsp, out);
}

// Round 8
// 123.502 us; speedup vs baseline: 1.0198x; 1.0095x over previous
//
#include <hip/hip_runtime.h>

#define NB    256   // neighbors
#define DIN   64
#define LATD  128
#define ECD   32

typedef __attribute__((ext_vector_type(8))) __bf16 bf16x8;
typedef __attribute__((ext_vector_type(4))) float f32x4;

#define XS_STRIDE 72   // row stride for WcT/WfT (bf16 elems)
#define EC_STRIDE 40   // 32 data + 8 pad (LDS bank spread)
#define WA_STRIDE 40

// d_ws layout (unsigned short elements)
#define WS_WC 0                     // WcT  [32][72]
#define WS_WF (32 * 72)             // WfT  [128][72]
#define WS_WA (32 * 72 + 128 * 72)  // WaTm [128][40]  (Wa rows 32..63, transposed, *log2e)
// WfT and WaTm are contiguous: one 14336-short (28672 B) staging chunk.
#define WSTAGE_SHORTS (128 * 72 + 128 * 40)
#define WA_OFF (128 * 72)           // offset of WaTm inside the staged chunk

#define MFMA(a, b, c) __builtin_amdgcn_mfma_f32_16x16x32_bf16((a), (b), (c), 0, 0, 0)

__device__ __forceinline__ unsigned short f2bf(float f) {
    unsigned u = __builtin_bit_cast(unsigned, f);
    u += 0x7fffu + ((u >> 16) & 1u);   // round-to-nearest-even
    return (unsigned short)(u >> 16);
}

// Packed f32->bf16 RNE: 1 instruction per 2 elements (gfx950; no builtin).
// Plain VALU op -> no TRANS hazard, safe as opaque asm (verified r2..r7).
__device__ __forceinline__ unsigned cvt2(float lo, float hi) {
    unsigned r;
    asm("v_cvt_pk_bf16_f32 %0, %1, %2" : "=v"(r) : "v"(lo), "v"(hi));
    return r;
}

// Single-instruction exp2. r4 LESSON: raw `asm("v_exp_f32")` FAILS —
// TRANS-op results need a wait state before a dependent VALU read and the
// compiler's hazard recognizer can't see through opaque asm (absmax 1.5).
// The builtin emits v_exp_f32 with compiler-managed hazards (r5 verified).
#if __has_builtin(__builtin_amdgcn_exp2f)
__device__ __forceinline__ float fexp2(float x) {
    return __builtin_amdgcn_exp2f(x);
}
#else
__device__ __forceinline__ float fexp2(float x) {
    float r;
    asm("v_exp_f32 %0, %1\n\ts_nop 1" : "=v"(r) : "v"(x));
    return r;
}
#endif

__device__ __forceinline__ bf16x8 pack8(float4 a, float4 b) {
    union { unsigned u[4]; bf16x8 v; } r;
    r.u[0] = cvt2(a.x, a.y);
    r.u[1] = cvt2(a.z, a.w);
    r.u[2] = cvt2(b.x, b.y);
    r.u[3] = cvt2(b.z, b.w);
    return r.v;
}

// Pre-transpose weights into bf16 B-fragment-friendly [n][k] layouts in d_ws.
// Wa rows 32..63 are pre-scaled by log2e so the kernel can use exp2 directly.
__global__ __launch_bounds__(256) void prep_kernel(
    const float* __restrict__ Wc, const float* __restrict__ Wf,
    const float* __restrict__ Wa, unsigned short* __restrict__ ws)
{
    int t = blockIdx.x * blockDim.x + threadIdx.x;
    int stride = gridDim.x * blockDim.x;
    for (int i = t; i < 32 * 64; i += stride) {
        int n = i >> 6, k = i & 63;
        ws[WS_WC + n * XS_STRIDE + k] = f2bf(Wc[k * ECD + n]);
    }
    for (int i = t; i < 128 * 64; i += stride) {
        int n = i >> 6, k = i & 63;
        ws[WS_WF + n * XS_STRIDE + k] = f2bf(Wf[k * LATD + n]);
    }
    for (int i = t; i < 128 * 32; i += stride) {
        int n = i >> 5, k = i & 31;
        ws[WS_WA + n * WA_STRIDE + k] = f2bf(Wa[(ECD + k) * LATD + n] * 1.44269504f);
    }
}

// r7 post-mortem: r5/r6/r7 all land 40-46 us despite 2x changes in serial
// path / ILP / block count, with NO pipe counter above ~20% -> consistent
// only with exposed-VMEM-latency (Little's law): per-g weight reloads from
// L2 (~250-600cy each, serially exposed by conservative vmcnt placement)
// dominate. THIS REV: zero VMEM in the g-loop — Wf/Wa/bf staged into LDS
// once per block (copy hidden under the X burst); g-loop reads weights via
// ds_read_b128 (~60cy, compiler handles lgkmcnt fine-grained — the known-
// good path per the m97 evidence). Structure otherwise identical to r7
// (2 elements interleaved, 4-tile waves, 512 blocks).
// Key algebra (verified): self_rep/mean_rep/ba constant along n -> cancel
// in softmax(axis=n); att = softmax_n(enc_comm @ Wa[32:64]); local_data /
// Wa[0:32] / Wa[64:96] / ba never touch the output.
__global__ __launch_bounds__(256, 2) void arm_main(
    const float* __restrict__ xg,   // neighbor [B][256][64]
    const float* __restrict__ bcv,  // bc [32]
    const float* __restrict__ bfv,  // bf [128]
    const float* __restrict__ wl,   // Wl [128][128]
    const float* __restrict__ blv,  // bl [128]
    const unsigned short* __restrict__ ws,
    float* __restrict__ out)        // [B][128]
{
    __shared__ unsigned short wstage[WSTAGE_SHORTS]; // 28672 B: WfT + WaTm
    __shared__ float bfs[LATD];                      // 512 B: bf
    __shared__ unsigned short ecs[NB * EC_STRIDE];   // 20480 B, bf16 enc_comm
    __shared__ float aggnum[2][4][LATD];             // [elem][wave][col]
    __shared__ float aggden[2][4][LATD];
    __shared__ float aggfull[2][LATD];
    __shared__ float wlpart[2][2][LATD];             // [khalf][elem][col]
    // total 60928 B (< 64 KB static cap; 2 blocks/CU)

    const int b0   = blockIdx.x;          // gridDim.x == 512
    const int b1   = blockIdx.x + 512;
    const int tid  = threadIdx.x;
    const int lane = tid & 63;
    const int w    = tid >> 6;   // wave id, owns rows 64w..64w+63 (4 m-tiles)
    const int l15  = lane & 15;
    const int q    = lane >> 4;

    // ---- issue weight-staging loads (L2, small) FIRST; they complete
    // before the X loads (in-order vmem queue), so the staging ds_writes
    // below don't wait on X. 1792 uint4 chunks = exactly 7 per thread.
    uint4 wch[7];
    {
        const uint4* src = reinterpret_cast<const uint4*>(ws + WS_WF);
        #pragma unroll
        for (int i = 0; i < 7; ++i)
            wch[i] = src[tid + i * 256];
    }
    uint4 bfch;
    if (tid < 32) bfch = reinterpret_cast<const uint4*>(bfv)[tid];

    // ---- element-invariant front-loads: Wc frags + bc (L2) ----
    bf16x8 wfrag[2][2];   // [khalf][colblock]
    #pragma unroll
    for (int ks = 0; ks < 2; ++ks)
        #pragma unroll
        for (int nb = 0; nb < 2; ++nb)
            wfrag[ks][nb] = *reinterpret_cast<const bf16x8*>(
                &ws[WS_WC + (nb * 16 + l15) * XS_STRIDE + ks * 32 + q * 8]);
    float bc0 = bcv[l15], bc1 = bcv[16 + l15];

    // ---- issue X loads for BOTH elements (32 dwordx4 in flight) ----
    // A-frag: row = lane&15 (within tile), k = quad*8 + j -> 8 contiguous floats.
    float4 st0[4][4], st1[4][4];
    {
        const float* xa = xg + (size_t)b0 * NB * DIN;
        const float* xc = xg + (size_t)b1 * NB * DIN;
        #pragma unroll
        for (int t = 0; t < 4; ++t) {
            const float* p = xa + (w * 64 + t * 16 + l15) * DIN + q * 8;
            st0[t][0] = *reinterpret_cast<const float4*>(p);
            st0[t][1] = *reinterpret_cast<const float4*>(p + 4);
            st0[t][2] = *reinterpret_cast<const float4*>(p + 32);
            st0[t][3] = *reinterpret_cast<const float4*>(p + 36);
        }
        #pragma unroll
        for (int t = 0; t < 4; ++t) {
            const float* p = xc + (w * 64 + t * 16 + l15) * DIN + q * 8;
            st1[t][0] = *reinterpret_cast<const float4*>(p);
            st1[t][1] = *reinterpret_cast<const float4*>(p + 4);
            st1[t][2] = *reinterpret_cast<const float4*>(p + 32);
            st1[t][3] = *reinterpret_cast<const float4*>(p + 36);
        }
    }

    // ---- write staged weights to LDS (waits only on the staging loads) ----
    {
        uint4* dst = reinterpret_cast<uint4*>(wstage);
        #pragma unroll
        for (int i = 0; i < 7; ++i)
            dst[tid + i * 256] = wch[i];
        if (tid < 32) reinterpret_cast<uint4*>(bfs)[tid] = bfch;
    }

    // ---- pack both elements into A-fragments (st regs die here) ----
    bf16x8 xfrag[2][4][2];
    #pragma unroll
    for (int t = 0; t < 4; ++t) {
        xfrag[0][t][0] = pack8(st0[t][0], st0[t][1]);
        xfrag[0][t][1] = pack8(st0[t][2], st0[t][3]);
    }
    #pragma unroll
    for (int t = 0; t < 4; ++t) {
        xfrag[1][t][0] = pack8(st1[t][0], st1[t][1]);
        xfrag[1][t][1] = pack8(st1[t][2], st1[t][3]);
    }

    // ---- enc_comm per element -> ecs -> ecfrag (same-wave rows; same-wave
    // DS ops execute in order, so no barrier needed for own rows) ----
    bf16x8 ecfrag[2][4];
    #pragma unroll
    for (int e = 0; e < 2; ++e) {
        #pragma unroll
        for (int t = 0; t < 4; ++t) {
            int rowA = w * 64 + t * 16;
            // bias folded into accumulator init (C/D col = lane&15 -> bias
            // uniform across the 4 result regs).
            f32x4 a0 = {bc0, bc0, bc0, bc0};
            f32x4 a1 = {bc1, bc1, bc1, bc1};
            #pragma unroll
            for (int ks = 0; ks < 2; ++ks) {
                a0 = MFMA(xfrag[e][t][ks], wfrag[ks][0], a0);
                a1 = MFMA(xfrag[e][t][ks], wfrag[ks][1], a1);
            }
            #pragma unroll
            for (int r = 0; r < 4; ++r) {
                int row = rowA + q * 4 + r;   // C/D: row = quad*4 + reg
                unsigned pk = cvt2(fmaxf(a0[r], 0.f), fmaxf(a1[r], 0.f));
                ecs[row * EC_STRIDE + l15]      = (unsigned short)pk;
                ecs[row * EC_STRIDE + 16 + l15] = (unsigned short)(pk >> 16);
            }
        }
        #pragma unroll
        for (int t = 0; t < 4; ++t)
            ecfrag[e][t] = *reinterpret_cast<const bf16x8*>(
                &ecs[(w * 64 + t * 16 + l15) * EC_STRIDE + q * 8]);
    }

    // staging visibility barrier: all wstage/bfs writes complete before any
    // wave's g-loop reads them (ecs accesses above are wave-private -> safe).
    __syncthreads();

    // ---- fused g-loop, both elements interleaved: enc_feature + logits +
    // unnormalized softmax agg. ZERO VMEM in this loop — weights via
    // ds_read_b128 (2-way bank aliasing only = free). No max-subtraction
    // (logits O(+-3); exp2 safe).
    for (int g = 0; g < 8; ++g) {
        const int r0 = g * 16 + l15;
        bf16x8 wf0 = *reinterpret_cast<const bf16x8*>(&wstage[r0 * XS_STRIDE + q * 8]);
        bf16x8 wf1 = *reinterpret_cast<const bf16x8*>(&wstage[r0 * XS_STRIDE + 32 + q * 8]);
        bf16x8 wag = *reinterpret_cast<const bf16x8*>(&wstage[WA_OFF + r0 * WA_STRIDE + q * 8]);
        float  bfl = bfs[r0];

        float num0 = 0.f, den0 = 0.f, num1 = 0.f, den1 = 0.f;
        #pragma unroll
        for (int t = 0; t < 4; ++t) {
            // element 0
            f32x4 za = {bfl, bfl, bfl, bfl};
            za = MFMA(xfrag[0][t][0], wf0, za);
            f32x4 efa = MFMA(xfrag[0][t][1], wf1, za);
            f32x4 zz0 = {0.f, 0.f, 0.f, 0.f};
            f32x4 lga = MFMA(ecfrag[0][t], wag, zz0);
            // element 1 (independent chain)
            f32x4 zb = {bfl, bfl, bfl, bfl};
            zb = MFMA(xfrag[1][t][0], wf0, zb);
            f32x4 efb = MFMA(xfrag[1][t][1], wf1, zb);
            f32x4 zz1 = {0.f, 0.f, 0.f, 0.f};
            f32x4 lgb = MFMA(ecfrag[1][t], wag, zz1);
            #pragma unroll
            for (int r = 0; r < 4; ++r) {
                float ea = fmaxf(efa[r], 0.f);
                float pa = fexp2(lga[r]);   // Wa pre-scaled by log2e in prep
                num0 = fmaf(pa, ea, num0);
                den0 += pa;
                float eb = fmaxf(efb[r], 0.f);
                float pb = fexp2(lgb[r]);
                num1 = fmaf(pb, eb, num1);
                den1 += pb;
            }
        }
        num0 += __shfl_xor(num0, 16, 64); num0 += __shfl_xor(num0, 32, 64);
        den0 += __shfl_xor(den0, 16, 64); den0 += __shfl_xor(den0, 32, 64);
        num1 += __shfl_xor(num1, 16, 64); num1 += __shfl_xor(num1, 32, 64);
        den1 += __shfl_xor(den1, 16, 64); den1 += __shfl_xor(den1, 32, 64);
        if (lane < 16) {
            aggnum[0][w][g * 16 + lane] = num0;
            aggden[0][w][g * 16 + lane] = den0;
            aggnum[1][w][g * 16 + lane] = num1;
            aggden[1][w][g * 16 + lane] = den1;
        }
    }
    __syncthreads();

    // ---- combine wave partials (both halves of the block active) ----
    {
        int e = tid >> 7, c = tid & 127;
        float num = aggnum[e][0][c] + aggnum[e][1][c] + aggnum[e][2][c] + aggnum[e][3][c];
        float den = aggden[e][0][c] + aggden[e][1][c] + aggden[e][2][c] + aggden[e][3][c];
        aggfull[e][c] = num / den;
    }
    __syncthreads();

    // ---- out = relu(agg @ Wl + bl): wl loaded ONCE, used for both elems ----
    {
        int c = tid & 127, h = tid >> 7;
        float acc0 = 0.f, acc1 = 0.f;
        #pragma unroll 16
        for (int k = h * 64; k < h * 64 + 64; ++k) {
            float wv = wl[k * LATD + c];
            acc0 = fmaf(aggfull[0][k], wv, acc0);
            acc1 = fmaf(aggfull[1][k], wv, acc1);
        }
        wlpart[h][0][c] = acc0;
        wlpart[h][1][c] = acc1;
    }
    __syncthreads();
    {
        int e = tid >> 7, c = tid & 127;
        out[(size_t)(e ? b1 : b0) * LATD + c] =
            fmaxf(wlpart[0][e][c] + wlpart[1][e][c] + blv[c], 0.f);
    }
}

extern "C" void kernel_launch(void* const* d_in, const int* in_sizes, int n_in,
                              void* d_out, int out_size, void* d_ws, size_t ws_size,
                              hipStream_t stream)
{
    const float* xg  = (const float*)d_in[1];
    const float* wc  = (const float*)d_in[2];
    const float* bc_ = (const float*)d_in[3];
    const float* wf  = (const float*)d_in[4];
    const float* bf_ = (const float*)d_in[5];
    const float* wa  = (const float*)d_in[6];
    const float* wl  = (const float*)d_in[8];
    const float* bl_ = (const float*)d_in[9];
    unsigned short* wsp = (unsigned short*)d_ws;   // needs 33,280 B of ws
    float* out = (float*)d_out;

    prep_kernel<<<8, 256, 0, stream>>>(wc, wf, wa, wsp);
    arm_main<<<512, 256, 0, stream>>>(xg, bc_, bf_, wl, bl_, wsp, out);
}